// Round 12
// baseline (318.006 us; speedup 1.0000x reference)
//
#include <hip/hip_runtime.h>
#include <cstdint>

typedef __bf16 bf16x8 __attribute__((ext_vector_type(8)));
typedef float  f32x4  __attribute__((ext_vector_type(4)));
typedef unsigned int u32x4 __attribute__((ext_vector_type(4)));
using u16 = unsigned short;

struct alignas(8) u16x4 { u16 x, y, z, w; };

__device__ __forceinline__ u16 f2bf(float f) {
  unsigned u = __builtin_bit_cast(unsigned, f);
  u = (u + 0x7FFFu + ((u >> 16) & 1u)) >> 16;   // RNE; inputs finite
  return (u16)u;
}
__device__ __forceinline__ float bf2f(u16 u) {
  unsigned v = ((unsigned)u) << 16;
  return __builtin_bit_cast(float, v);
}

// ---------------- ws layout (bytes) ----------------
static constexpr size_t OFF_XBF  = 0;
static constexpr size_t OFF_T2   = 33554432;       // bf16 (16 MB)
static constexpr size_t OFF_PM   = 67108864;       // means partials, 4 MB
static constexpr size_t OFF_RW   = 167772160;      // bf16 RW' = RW + R (16 MB)
static constexpr size_t OFF_LG   = 201326592;      // logits [64][8]
static constexpr size_t OFF_G    = 201588736;
static constexpr size_t OFF_RB   = 201592832;
static constexpr size_t WS_NEED  = 201887744;

// ---------- chunk means (16-row segments) + x -> bf16, float4 vectorized ----------
__global__ __launch_bounds__(256) void k_means(const float* __restrict__ x,
                                               float* __restrict__ pm,
                                               u16* __restrict__ xbf) {
  int b = blockIdx.x, q = blockIdx.y, tid = threadIdx.x;
  const float* xb = x + (size_t)b * 262144 + (size_t)q * 16384 + tid * 4;
  u16* xo = xbf + (size_t)b * 262144 + (size_t)q * 16384 + tid * 4;
  float s0 = 0.f, s1 = 0.f, s2 = 0.f, s3 = 0.f;
#pragma unroll
  for (int t = 0; t < 16; ++t) {
    float4 v = *(const float4*)(xb + t * 1024);
    s0 += v.x; s1 += v.y; s2 += v.z; s3 += v.w;
    u16x4 o; o.x = f2bf(v.x); o.y = f2bf(v.y); o.z = f2bf(v.z); o.w = f2bf(v.w);
    *(u16x4*)(xo + t * 1024) = o;
  }
  float4 sv; sv.x = s0; sv.y = s1; sv.z = s2; sv.w = s3;
  *(float4*)(pm + ((size_t)b * 16 + q) * 1024 + tid * 4) = sv;
}

// ---------- reduce partial means + logits GEMV (standalone again) ----------
__global__ __launch_bounds__(256) void k_redlogits(const float* __restrict__ pm,
                                                   const float* __restrict__ w_gate,
                                                   float* __restrict__ logits) {
  __shared__ float red[4][8];
  int b = blockIdx.x, tid = threadIdx.x;
  const float* p = pm + (size_t)b * 16384 + tid * 4;
  float4 s = {0.f, 0.f, 0.f, 0.f};
#pragma unroll
  for (int q = 0; q < 16; ++q) {
    float4 v = *(const float4*)(p + q * 1024);
    s.x += v.x; s.y += v.y; s.z += v.z; s.w += v.w;
  }
  int i0 = tid * 4;
  float acc[8];
#pragma unroll
  for (int e = 0; e < 8; ++e) {
    acc[e] = s.x * w_gate[(i0 + 0) * 8 + e] + s.y * w_gate[(i0 + 1) * 8 + e]
           + s.z * w_gate[(i0 + 2) * 8 + e] + s.w * w_gate[(i0 + 3) * 8 + e];
  }
#pragma unroll
  for (int off = 32; off >= 1; off >>= 1)
#pragma unroll
    for (int e = 0; e < 8; ++e) acc[e] += __shfl_down(acc[e], off, 64);
  int wv = tid >> 6;
  if ((tid & 63) == 0)
#pragma unroll
    for (int e = 0; e < 8; ++e) red[wv][e] = acc[e];
  __syncthreads();
  if (tid < 8)
    logits[b * 8 + tid] =
        (red[0][tid] + red[1][tid] + red[2][tid] + red[3][tid]) * (1.f / 256.f);
}

// ---------- mergeA (+rb tail at bx==128): T2t[e][lm][o] (bf16) ----------
__global__ __launch_bounds__(256) void k_mergeA(const float* __restrict__ W,
                                                const float* __restrict__ R,
                                                const float* __restrict__ c1o,
                                                const float* __restrict__ c2o,
                                                u16* __restrict__ T2t,
                                                const float* __restrict__ bias,
                                                const float* __restrict__ res_bias,
                                                const float* __restrict__ c1b,
                                                const float* __restrict__ c2b,
                                                float* __restrict__ rb) {
  int e = blockIdx.y, bx = blockIdx.x, tid = threadIdx.x;
  if (bx == 128) {
    __shared__ float rb0[32][33], rb1[32][33], m1b[32][32], m2b[32][32];
    for (int idx = tid; idx < 1024; idx += 256) {
      int i = idx >> 5, j = idx & 31;
      rb0[i][j] = bias[e * 1024 + idx] - res_bias[idx];
      m1b[i][j] = c1b[e * 1024 + idx];
      m2b[i][j] = c2b[e * 1024 + idx];
    }
    __syncthreads();
    for (int idx = tid; idx < 1024; idx += 256) {
      int p = idx >> 5, j = idx & 31;
      float s = 0.f;
#pragma unroll
      for (int i = 0; i < 32; ++i) s += m1b[p][i] * rb0[i][j];
      rb1[p][j] = s;
    }
    __syncthreads();
    for (int idx = tid; idx < 1024; idx += 256) {
      int p = idx >> 5, q = idx & 31;
      float s = 0.f;
#pragma unroll
      for (int j = 0; j < 32; ++j) s += m2b[q][j] * rb1[p][j];
      rb[e * 1024 + idx] = s;
    }
    return;
  }
  __shared__ float dw[8 * 1024];        // [c][jk]
  __shared__ float m1[1024], m2[1024];
  int c0 = bx * 8;
  const float* We = W + (size_t)e * 1048576;
  for (int idx = tid; idx < 1024; idx += 256) {
    m1[idx] = c1o[e * 1024 + idx];
    m2[idx] = c2o[e * 1024 + idx];
  }
  {
    int r = tid >> 1, h = (tid & 1) * 4;
#pragma unroll
    for (int i = 0; i < 8; ++i) {
      int row = r + i * 128;
      const float4 wv = *(const float4*)(We + (size_t)row * 1024 + c0 + h);
      const float4 rv = *(const float4*)(R + (size_t)row * 1024 + c0 + h);
      dw[(h + 0) * 1024 + row] = wv.x - rv.x;
      dw[(h + 1) * 1024 + row] = wv.y - rv.y;
      dw[(h + 2) * 1024 + row] = wv.z - rv.z;
      dw[(h + 3) * 1024 + row] = wv.w - rv.w;
    }
  }
  __syncthreads();
  int i1 = tid & 31, c = tid >> 5;
  const float* dwc = dw + c * 1024;
  float U[32];
#pragma unroll
  for (int k = 0; k < 32; ++k) U[k] = 0.f;
  for (int j = 0; j < 32; ++j) {
    float cj = m1[i1 * 32 + j];
    const float4* rowp = (const float4*)(dwc + j * 32);
#pragma unroll
    for (int k4 = 0; k4 < 8; ++k4) {
      float4 v = rowp[k4];
      U[k4 * 4 + 0] += cj * v.x; U[k4 * 4 + 1] += cj * v.y;
      U[k4 * 4 + 2] += cj * v.z; U[k4 * 4 + 3] += cj * v.w;
    }
  }
  u16* obase = T2t + (size_t)e * 1048576 + (size_t)(c0 + c) * 1024 + i1 * 32;
#pragma unroll
  for (int g4 = 0; g4 < 8; ++g4) {
    float s[4];
#pragma unroll
    for (int q = 0; q < 4; ++q) {
      const float4* m2r = (const float4*)(m2 + (g4 * 4 + q) * 32);
      float acc = 0.f;
#pragma unroll
      for (int k4 = 0; k4 < 8; ++k4) {
        float4 mv = m2r[k4];
        acc += mv.x * U[k4 * 4 + 0] + mv.y * U[k4 * 4 + 1]
             + mv.z * U[k4 * 4 + 2] + mv.w * U[k4 * 4 + 3];
      }
      s[q] = acc;
    }
    u16x4 o4; o4.x = f2bf(s[0]); o4.y = f2bf(s[1]); o4.z = f2bf(s[2]); o4.w = f2bf(s[3]);
    *(u16x4*)(obase + g4 * 4) = o4;
  }
}

// ---------- mergeB (+gatefin tail): RW'[e][o][i] = bf16( R[o][i] + sum C1i C2i T2t ) ----------
__global__ __launch_bounds__(256) void k_mergeB(const u16* __restrict__ T2t,
                                                const float* __restrict__ c1i,
                                                const float* __restrict__ c2i,
                                                const float* __restrict__ R,
                                                u16* __restrict__ RWbf,
                                                const float* __restrict__ logits,
                                                float* __restrict__ g,
                                                float* __restrict__ loss_out) {
  int e = blockIdx.y, bx = blockIdx.x, tid = threadIdx.x;
  if (bx == 128) {
    if (e != 0) return;
    __shared__ float gates[64][8];
    __shared__ float imp[8];
    if (tid < 64) {
      float lg[8];
#pragma unroll
      for (int j = 0; j < 8; ++j) lg[j] = logits[tid * 8 + j];
      float mx = lg[0];
#pragma unroll
      for (int j = 1; j < 8; ++j) mx = fmaxf(mx, lg[j]);
      float s = 0.f, ex[8];
#pragma unroll
      for (int j = 0; j < 8; ++j) { ex[j] = expf(lg[j] - mx); s += ex[j]; }
      float inv = 1.f / s;
#pragma unroll
      for (int j = 0; j < 8; ++j) gates[tid][j] = ex[j] * inv;
    }
    __syncthreads();
    if (tid < 8) {
      float s = 0.f;
      for (int bb = 0; bb < 64; ++bb) s += gates[bb][tid];
      imp[tid] = s;
    }
    __syncthreads();
    if (tid == 0) {
      float mean = 0.f;
#pragma unroll
      for (int j = 0; j < 8; ++j) mean += imp[j];
      mean *= (1.f / 8.f);
      float var = 0.f;
#pragma unroll
      for (int j = 0; j < 8; ++j) { float d = imp[j] - mean; var += d * d; }
      var *= (1.f / 7.f);                         // ddof=1
      loss_out[0] = (var / (mean * mean + 1e-10f)) * 1e-5f;
    }
    __syncthreads();
    if (tid < 64) {
      int src = ((tid & 7) == 0) ? tid : tid - 1; // roll by one chunk, keep first
#pragma unroll
      for (int j = 0; j < 8; ++j) g[tid * 8 + j] = gates[src][j];
    }
    return;
  }
  __shared__ float t2[8 * 1024];        // [oc][lm]
  __shared__ float m1[1024], m2[1024];
  int o0 = bx * 8;
  const u16* Te = T2t + (size_t)e * 1048576;
  for (int idx = tid; idx < 1024; idx += 256) {
    m1[idx] = c1i[e * 1024 + idx];
    m2[idx] = c2i[e * 1024 + idx];
  }
  {
    int r = tid >> 1, h = (tid & 1) * 4;
#pragma unroll
    for (int i = 0; i < 8; ++i) {
      int row = r + i * 128;
      const u16x4 tv = *(const u16x4*)(Te + (size_t)row * 1024 + o0 + h);
      t2[(h + 0) * 1024 + row] = bf2f(tv.x);
      t2[(h + 1) * 1024 + row] = bf2f(tv.y);
      t2[(h + 2) * 1024 + row] = bf2f(tv.z);
      t2[(h + 3) * 1024 + row] = bf2f(tv.w);
    }
  }
  __syncthreads();
  int i1 = tid & 31, oc = tid >> 5;
  const float* t2c = t2 + oc * 1024;
  float A[32];
#pragma unroll
  for (int m = 0; m < 32; ++m) A[m] = 0.f;
  for (int l = 0; l < 32; ++l) {
    float cl = m1[i1 * 32 + l];
    const float4* rowp = (const float4*)(t2c + l * 32);
#pragma unroll
    for (int m4 = 0; m4 < 8; ++m4) {
      float4 v = rowp[m4];
      A[m4 * 4 + 0] += cl * v.x; A[m4 * 4 + 1] += cl * v.y;
      A[m4 * 4 + 2] += cl * v.z; A[m4 * 4 + 3] += cl * v.w;
    }
  }
  const float* Rrow = R + (size_t)(o0 + oc) * 1024 + i1 * 32;
  u16* obase = RWbf + ((size_t)e * 1024 + o0 + oc) * 1024 + i1 * 32;
#pragma unroll
  for (int g4 = 0; g4 < 8; ++g4) {
    float s[4];
#pragma unroll
    for (int q = 0; q < 4; ++q) {
      const float4* m2r = (const float4*)(m2 + (g4 * 4 + q) * 32);
      float acc = Rrow[g4 * 4 + q];               // fold residual: RW' = R + merged
#pragma unroll
      for (int m4 = 0; m4 < 8; ++m4) {
        float4 mv = m2r[m4];
        acc += mv.x * A[m4 * 4 + 0] + mv.y * A[m4 * 4 + 1]
             + mv.z * A[m4 * 4 + 2] + mv.w * A[m4 * 4 + 3];
      }
      s[q] = acc;
    }
    u16x4 o4; o4.x = f2bf(s[0]); o4.y = f2bf(s[1]); o4.z = f2bf(s[2]); o4.w = f2bf(s[3]);
    *(u16x4*)(obase + g4 * 4) = o4;
  }
}

// ---------- fused GEMM: B-tile = sum_e g[b][e] * RW'[e] computed on the fly ----------
// 256x256 tile, BK=64, 8 waves, reg-staged A dbuf, L2-pinned RW' stripe per XCD:
// xcd = nt*2 + chunk-half -> the 4MB RW' nt-stripe stays in that XCD's L2,
// shared by its 32 CUs (fabric reads ~32MB instead of 1GB; EW buffer eliminated).
__global__ __launch_bounds__(512) void k_gemm(const u16* __restrict__ Xb,
                                              const u16* __restrict__ RWbf,
                                              const float* __restrict__ rb,
                                              const float* __restrict__ res_b,
                                              const float* __restrict__ g,
                                              float* __restrict__ Y) {
  __shared__ alignas(16) u16 As[2][256 * 64];
  __shared__ alignas(16) u16 Bs[2][256 * 64];
  int hw = blockIdx.x;
  int nt = (hw & 7) >> 1;                 // 4 col-stripes, 2 XCDs each
  int b  = (hw & 1) * 32 + (hw >> 3);     // chunk
  int t0 = b * 256, o0 = nt * 256;
  int tid = threadIdx.x, lane = tid & 63, wv = tid >> 6;
  int wr = wv >> 2, wc = wv & 3;          // 2x4 wave grid, 128x64 each
  f32x4 acc[8][4] = {};
  const u16* aG = Xb + (size_t)t0 * 1024;
  const u16* bG = RWbf + (size_t)o0 * 1024;   // + e*1048576 per expert
  float ge[8];
#pragma unroll
  for (int e = 0; e < 8; ++e) ge[e] = g[b * 8 + e];
  // A staging geometry (512 thr): rows srow+iss*64, col group tid&7
  int srow = tid >> 3;
  int kcol = (tid & 7) << 3;
  // B combine geometry: row rB = tid>>1 (0..255), groups q: col (tid&1)*32+q*8
  int rB = tid >> 1;
  int cB0 = (tid & 1) * 32;
  int gB0 = (tid & 1) * 4;                // group index base (col/8)
  int lr = lane & 15;
  int sx = lr & 7;
  u32x4 la[4];
#pragma unroll
  for (int iss = 0; iss < 4; ++iss) {
    int r = srow + iss * 64;
    la[iss] = *(const u32x4*)(aG + (size_t)r * 1024 + kcol);
  }
  for (int kt = 0; kt < 16; ++kt) {
    int cur = kt & 1;
    int k0 = kt << 6;
    // write prefetched A regs
#pragma unroll
    for (int iss = 0; iss < 4; ++iss) {
      int r = srow + iss * 64;
      int wcl = (((tid & 7) ^ (r & 7)) << 3);
      *(u32x4*)&As[cur][r * 64 + wcl] = la[iss];
    }
    // B: load 8 experts, combine, pack, write (per 16B group)
    const u16* bRow = bG + (size_t)rB * 1024 + k0 + cB0;
#pragma unroll
    for (int q = 0; q < 4; ++q) {
      float fa[8];
#pragma unroll
      for (int j = 0; j < 8; ++j) fa[j] = 0.f;
#pragma unroll
      for (int e = 0; e < 8; ++e) {
        u32x4 v = *(const u32x4*)(bRow + (size_t)e * 1048576 + q * 8);
        float w = ge[e];
#pragma unroll
        for (int h = 0; h < 4; ++h) {
          unsigned lo = v[h] << 16;
          unsigned hi = v[h] & 0xFFFF0000u;
          fa[2 * h]     += w * __builtin_bit_cast(float, lo);
          fa[2 * h + 1] += w * __builtin_bit_cast(float, hi);
        }
      }
      u32x4 pk;
#pragma unroll
      for (int h = 0; h < 4; ++h)
        pk[h] = (unsigned)f2bf(fa[2 * h]) | ((unsigned)f2bf(fa[2 * h + 1]) << 16);
      int gq = gB0 + q;
      *(u32x4*)&Bs[cur][rB * 64 + ((gq ^ (rB & 7)) << 3)] = pk;
    }
    __syncthreads();
    if (kt < 15) {
      int k0n = (kt + 1) << 6;
#pragma unroll
      for (int iss = 0; iss < 4; ++iss) {
        int r = srow + iss * 64;
        la[iss] = *(const u32x4*)(aG + (size_t)r * 1024 + k0n + kcol);
      }
    }
#pragma unroll
    for (int kk = 0; kk < 2; ++kk) {
      int c16 = kk * 4 + (lane >> 4);
      int cp = ((c16 ^ sx) << 3);
      bf16x8 af[8], bfr[4];
#pragma unroll
      for (int mi = 0; mi < 8; ++mi)
        af[mi] = *(const bf16x8*)&As[cur][(wr * 128 + mi * 16 + lr) * 64 + cp];
#pragma unroll
      for (int ni = 0; ni < 4; ++ni)
        bfr[ni] = *(const bf16x8*)&Bs[cur][(wc * 64 + ni * 16 + lr) * 64 + cp];
#pragma unroll
      for (int mi = 0; mi < 8; ++mi)
#pragma unroll
        for (int ni = 0; ni < 4; ++ni)
          acc[mi][ni] = __builtin_amdgcn_mfma_f32_16x16x32_bf16(af[mi], bfr[ni], acc[mi][ni], 0, 0, 0);
    }
    // single barrier per iter (R10-validated): next iter writes buf^1 only.
  }
  int rbase = (lane >> 4) << 2;
#pragma unroll
  for (int ni = 0; ni < 4; ++ni) {
    int o = o0 + wc * 64 + ni * 16 + lr;
    float ebv = res_b[o];
#pragma unroll
    for (int e = 0; e < 8; ++e) ebv += ge[e] * rb[e * 1024 + o];
#pragma unroll
    for (int mi = 0; mi < 8; ++mi) {
      int trow = t0 + wr * 128 + mi * 16 + rbase;
      float* yp = Y + (size_t)trow * 1024 + o;
      yp[0]    = acc[mi][ni][0] + ebv;
      yp[1024] = acc[mi][ni][1] + ebv;
      yp[2048] = acc[mi][ni][2] + ebv;
      yp[3072] = acc[mi][ni][3] + ebv;
    }
  }
}

extern "C" void kernel_launch(void* const* d_in, const int* in_sizes, int n_in,
                              void* d_out, int out_size, void* d_ws, size_t ws_size,
                              hipStream_t stream) {
  const float* x      = (const float*)d_in[0];
  const float* w_gate = (const float*)d_in[1];
  const float* weight = (const float*)d_in[2];
  const float* bias   = (const float*)d_in[3];
  const float* res_w  = (const float*)d_in[4];
  const float* res_b  = (const float*)d_in[5];
  const float* c1i    = (const float*)d_in[6];
  const float* c2i    = (const float*)d_in[7];
  const float* c1o    = (const float*)d_in[8];
  const float* c2o    = (const float*)d_in[9];
  const float* c1b    = (const float*)d_in[10];
  const float* c2b    = (const float*)d_in[11];
  float* y = (float*)d_out;

  if (ws_size < WS_NEED) return;

  char* wsb = (char*)d_ws;
  u16*   xbf   = (u16*)(wsb + OFF_XBF);
  u16*   T2t   = (u16*)(wsb + OFF_T2);
  float* pm    = (float*)(wsb + OFF_PM);
  u16*   RWbf  = (u16*)(wsb + OFF_RW);
  float* lgts  = (float*)(wsb + OFF_LG);
  float* g     = (float*)(wsb + OFF_G);
  float* rb    = (float*)(wsb + OFF_RB);

  k_means    <<<dim3(64, 16), 256, 0, stream>>>(x, pm, xbf);
  k_redlogits<<<64, 256, 0, stream>>>(pm, w_gate, lgts);
  k_mergeA   <<<dim3(129, 8), 256, 0, stream>>>(weight, res_w, c1o, c2o, T2t,
                                                bias, res_b, c1b, c2b, rb);
  k_mergeB   <<<dim3(129, 8), 256, 0, stream>>>(T2t, c1i, c2i, res_w, RWbf,
                                                lgts, g, y + 16777216);
  k_gemm     <<<256, 512, 0, stream>>>(xbf, RWbf, rb, res_b, g, y);
}

// Round 13
// 293.230 us; speedup vs baseline: 1.0845x; 1.0845x over previous
//
#include <hip/hip_runtime.h>
#include <cstdint>

typedef __bf16 bf16x8 __attribute__((ext_vector_type(8)));
typedef float  f32x4  __attribute__((ext_vector_type(4)));
typedef unsigned int u32x4 __attribute__((ext_vector_type(4)));
using u16 = unsigned short;

struct alignas(8) u16x4 { u16 x, y, z, w; };

__device__ __forceinline__ u16 f2bf(float f) {
  unsigned u = __builtin_bit_cast(unsigned, f);
  u = (u + 0x7FFFu + ((u >> 16) & 1u)) >> 16;   // RNE; inputs finite
  return (u16)u;
}
__device__ __forceinline__ float bf2f(u16 u) {
  unsigned v = ((unsigned)u) << 16;
  return __builtin_bit_cast(float, v);
}

// ---------------- ws layout (bytes) ----------------
static constexpr size_t OFF_XBF  = 0;
static constexpr size_t OFF_T2   = 33554432;       // bf16 (16 MB)
static constexpr size_t OFF_PM   = 67108864;       // means partials, 4 MB
static constexpr size_t OFF_RW   = 167772160;      // bf16 RW' = RW + R (16 MB)
static constexpr size_t OFF_LG   = 201326592;      // logits [64][8]
static constexpr size_t OFF_G    = 201588736;
static constexpr size_t OFF_RB   = 201592832;
static constexpr size_t WS_NEED  = 201887744;

// ---------- chunk means (16-row segments) + x -> bf16, float4 vectorized ----------
__global__ __launch_bounds__(256) void k_means(const float* __restrict__ x,
                                               float* __restrict__ pm,
                                               u16* __restrict__ xbf) {
  int b = blockIdx.x, q = blockIdx.y, tid = threadIdx.x;
  const float* xb = x + (size_t)b * 262144 + (size_t)q * 16384 + tid * 4;
  u16* xo = xbf + (size_t)b * 262144 + (size_t)q * 16384 + tid * 4;
  float s0 = 0.f, s1 = 0.f, s2 = 0.f, s3 = 0.f;
#pragma unroll
  for (int t = 0; t < 16; ++t) {
    float4 v = *(const float4*)(xb + t * 1024);
    s0 += v.x; s1 += v.y; s2 += v.z; s3 += v.w;
    u16x4 o; o.x = f2bf(v.x); o.y = f2bf(v.y); o.z = f2bf(v.z); o.w = f2bf(v.w);
    *(u16x4*)(xo + t * 1024) = o;
  }
  float4 sv; sv.x = s0; sv.y = s1; sv.z = s2; sv.w = s3;
  *(float4*)(pm + ((size_t)b * 16 + q) * 1024 + tid * 4) = sv;
}

// ---------- reduce partial means + logits GEMV ----------
__global__ __launch_bounds__(256) void k_redlogits(const float* __restrict__ pm,
                                                   const float* __restrict__ w_gate,
                                                   float* __restrict__ logits) {
  __shared__ float red[4][8];
  int b = blockIdx.x, tid = threadIdx.x;
  const float* p = pm + (size_t)b * 16384 + tid * 4;
  float4 s = {0.f, 0.f, 0.f, 0.f};
#pragma unroll
  for (int q = 0; q < 16; ++q) {
    float4 v = *(const float4*)(p + q * 1024);
    s.x += v.x; s.y += v.y; s.z += v.z; s.w += v.w;
  }
  int i0 = tid * 4;
  float acc[8];
#pragma unroll
  for (int e = 0; e < 8; ++e) {
    acc[e] = s.x * w_gate[(i0 + 0) * 8 + e] + s.y * w_gate[(i0 + 1) * 8 + e]
           + s.z * w_gate[(i0 + 2) * 8 + e] + s.w * w_gate[(i0 + 3) * 8 + e];
  }
#pragma unroll
  for (int off = 32; off >= 1; off >>= 1)
#pragma unroll
    for (int e = 0; e < 8; ++e) acc[e] += __shfl_down(acc[e], off, 64);
  int wv = tid >> 6;
  if ((tid & 63) == 0)
#pragma unroll
    for (int e = 0; e < 8; ++e) red[wv][e] = acc[e];
  __syncthreads();
  if (tid < 8)
    logits[b * 8 + tid] =
        (red[0][tid] + red[1][tid] + red[2][tid] + red[3][tid]) * (1.f / 256.f);
}

// ---------- mergeA (+rb tail at bx==128): T2t[e][lm][o] (bf16) ----------
__global__ __launch_bounds__(256) void k_mergeA(const float* __restrict__ W,
                                                const float* __restrict__ R,
                                                const float* __restrict__ c1o,
                                                const float* __restrict__ c2o,
                                                u16* __restrict__ T2t,
                                                const float* __restrict__ bias,
                                                const float* __restrict__ res_bias,
                                                const float* __restrict__ c1b,
                                                const float* __restrict__ c2b,
                                                float* __restrict__ rb) {
  int e = blockIdx.y, bx = blockIdx.x, tid = threadIdx.x;
  if (bx == 128) {
    __shared__ float rb0[32][33], rb1[32][33], m1b[32][32], m2b[32][32];
    for (int idx = tid; idx < 1024; idx += 256) {
      int i = idx >> 5, j = idx & 31;
      rb0[i][j] = bias[e * 1024 + idx] - res_bias[idx];
      m1b[i][j] = c1b[e * 1024 + idx];
      m2b[i][j] = c2b[e * 1024 + idx];
    }
    __syncthreads();
    for (int idx = tid; idx < 1024; idx += 256) {
      int p = idx >> 5, j = idx & 31;
      float s = 0.f;
#pragma unroll
      for (int i = 0; i < 32; ++i) s += m1b[p][i] * rb0[i][j];
      rb1[p][j] = s;
    }
    __syncthreads();
    for (int idx = tid; idx < 1024; idx += 256) {
      int p = idx >> 5, q = idx & 31;
      float s = 0.f;
#pragma unroll
      for (int j = 0; j < 32; ++j) s += m2b[q][j] * rb1[p][j];
      rb[e * 1024 + idx] = s;
    }
    return;
  }
  __shared__ float dw[8 * 1024];        // [c][jk]
  __shared__ float m1[1024], m2[1024];
  int c0 = bx * 8;
  const float* We = W + (size_t)e * 1048576;
  for (int idx = tid; idx < 1024; idx += 256) {
    m1[idx] = c1o[e * 1024 + idx];
    m2[idx] = c2o[e * 1024 + idx];
  }
  {
    int r = tid >> 1, h = (tid & 1) * 4;
#pragma unroll
    for (int i = 0; i < 8; ++i) {
      int row = r + i * 128;
      const float4 wv = *(const float4*)(We + (size_t)row * 1024 + c0 + h);
      const float4 rv = *(const float4*)(R + (size_t)row * 1024 + c0 + h);
      dw[(h + 0) * 1024 + row] = wv.x - rv.x;
      dw[(h + 1) * 1024 + row] = wv.y - rv.y;
      dw[(h + 2) * 1024 + row] = wv.z - rv.z;
      dw[(h + 3) * 1024 + row] = wv.w - rv.w;
    }
  }
  __syncthreads();
  int i1 = tid & 31, c = tid >> 5;
  const float* dwc = dw + c * 1024;
  float U[32];
#pragma unroll
  for (int k = 0; k < 32; ++k) U[k] = 0.f;
  for (int j = 0; j < 32; ++j) {
    float cj = m1[i1 * 32 + j];
    const float4* rowp = (const float4*)(dwc + j * 32);
#pragma unroll
    for (int k4 = 0; k4 < 8; ++k4) {
      float4 v = rowp[k4];
      U[k4 * 4 + 0] += cj * v.x; U[k4 * 4 + 1] += cj * v.y;
      U[k4 * 4 + 2] += cj * v.z; U[k4 * 4 + 3] += cj * v.w;
    }
  }
  u16* obase = T2t + (size_t)e * 1048576 + (size_t)(c0 + c) * 1024 + i1 * 32;
#pragma unroll
  for (int g4 = 0; g4 < 8; ++g4) {
    float s[4];
#pragma unroll
    for (int q = 0; q < 4; ++q) {
      const float4* m2r = (const float4*)(m2 + (g4 * 4 + q) * 32);
      float acc = 0.f;
#pragma unroll
      for (int k4 = 0; k4 < 8; ++k4) {
        float4 mv = m2r[k4];
        acc += mv.x * U[k4 * 4 + 0] + mv.y * U[k4 * 4 + 1]
             + mv.z * U[k4 * 4 + 2] + mv.w * U[k4 * 4 + 3];
      }
      s[q] = acc;
    }
    u16x4 o4; o4.x = f2bf(s[0]); o4.y = f2bf(s[1]); o4.z = f2bf(s[2]); o4.w = f2bf(s[3]);
    *(u16x4*)(obase + g4 * 4) = o4;
  }
}

// ---------- mergeB (+gatefin tail): RW'[e][o][i] = bf16( R[o][i] + sum C1i C2i T2t ) ----------
__global__ __launch_bounds__(256) void k_mergeB(const u16* __restrict__ T2t,
                                                const float* __restrict__ c1i,
                                                const float* __restrict__ c2i,
                                                const float* __restrict__ R,
                                                u16* __restrict__ RWbf,
                                                const float* __restrict__ logits,
                                                float* __restrict__ g,
                                                float* __restrict__ loss_out) {
  int e = blockIdx.y, bx = blockIdx.x, tid = threadIdx.x;
  if (bx == 128) {
    if (e != 0) return;
    __shared__ float gates[64][8];
    __shared__ float imp[8];
    if (tid < 64) {
      float lg[8];
#pragma unroll
      for (int j = 0; j < 8; ++j) lg[j] = logits[tid * 8 + j];
      float mx = lg[0];
#pragma unroll
      for (int j = 1; j < 8; ++j) mx = fmaxf(mx, lg[j]);
      float s = 0.f, ex[8];
#pragma unroll
      for (int j = 0; j < 8; ++j) { ex[j] = expf(lg[j] - mx); s += ex[j]; }
      float inv = 1.f / s;
#pragma unroll
      for (int j = 0; j < 8; ++j) gates[tid][j] = ex[j] * inv;
    }
    __syncthreads();
    if (tid < 8) {
      float s = 0.f;
      for (int bb = 0; bb < 64; ++bb) s += gates[bb][tid];
      imp[tid] = s;
    }
    __syncthreads();
    if (tid == 0) {
      float mean = 0.f;
#pragma unroll
      for (int j = 0; j < 8; ++j) mean += imp[j];
      mean *= (1.f / 8.f);
      float var = 0.f;
#pragma unroll
      for (int j = 0; j < 8; ++j) { float d = imp[j] - mean; var += d * d; }
      var *= (1.f / 7.f);                         // ddof=1
      loss_out[0] = (var / (mean * mean + 1e-10f)) * 1e-5f;
    }
    __syncthreads();
    if (tid < 64) {
      int src = ((tid & 7) == 0) ? tid : tid - 1; // roll by one chunk, keep first
#pragma unroll
      for (int j = 0; j < 8; ++j) g[tid * 8 + j] = gates[src][j];
    }
    return;
  }
  __shared__ float t2[8 * 1024];        // [oc][lm]
  __shared__ float m1[1024], m2[1024];
  int o0 = bx * 8;
  const u16* Te = T2t + (size_t)e * 1048576;
  for (int idx = tid; idx < 1024; idx += 256) {
    m1[idx] = c1i[e * 1024 + idx];
    m2[idx] = c2i[e * 1024 + idx];
  }
  {
    int r = tid >> 1, h = (tid & 1) * 4;
#pragma unroll
    for (int i = 0; i < 8; ++i) {
      int row = r + i * 128;
      const u16x4 tv = *(const u16x4*)(Te + (size_t)row * 1024 + o0 + h);
      t2[(h + 0) * 1024 + row] = bf2f(tv.x);
      t2[(h + 1) * 1024 + row] = bf2f(tv.y);
      t2[(h + 2) * 1024 + row] = bf2f(tv.z);
      t2[(h + 3) * 1024 + row] = bf2f(tv.w);
    }
  }
  __syncthreads();
  int i1 = tid & 31, oc = tid >> 5;
  const float* t2c = t2 + oc * 1024;
  float A[32];
#pragma unroll
  for (int m = 0; m < 32; ++m) A[m] = 0.f;
  for (int l = 0; l < 32; ++l) {
    float cl = m1[i1 * 32 + l];
    const float4* rowp = (const float4*)(t2c + l * 32);
#pragma unroll
    for (int m4 = 0; m4 < 8; ++m4) {
      float4 v = rowp[m4];
      A[m4 * 4 + 0] += cl * v.x; A[m4 * 4 + 1] += cl * v.y;
      A[m4 * 4 + 2] += cl * v.z; A[m4 * 4 + 3] += cl * v.w;
    }
  }
  const float* Rrow = R + (size_t)(o0 + oc) * 1024 + i1 * 32;
  u16* obase = RWbf + ((size_t)e * 1024 + o0 + oc) * 1024 + i1 * 32;
#pragma unroll
  for (int g4 = 0; g4 < 8; ++g4) {
    float s[4];
#pragma unroll
    for (int q = 0; q < 4; ++q) {
      const float4* m2r = (const float4*)(m2 + (g4 * 4 + q) * 32);
      float acc = Rrow[g4 * 4 + q];               // fold residual: RW' = R + merged
#pragma unroll
      for (int m4 = 0; m4 < 8; ++m4) {
        float4 mv = m2r[m4];
        acc += mv.x * A[m4 * 4 + 0] + mv.y * A[m4 * 4 + 1]
             + mv.z * A[m4 * 4 + 2] + mv.w * A[m4 * 4 + 3];
      }
      s[q] = acc;
    }
    u16x4 o4; o4.x = f2bf(s[0]); o4.y = f2bf(s[1]); o4.z = f2bf(s[2]); o4.w = f2bf(s[3]);
    *(u16x4*)(obase + g4 * 4) = o4;
  }
}

// ---------- fused GEMM (retry, 16 waves): B-tile = sum_e g[b][e]*RW'[e] on the fly ----------
// 1024 thr: acc[4][4]=64 VGPR (vs R12's 128) -> fits the 128-VGPR/16-wave cap, no spill.
// L2-pin: nt-stripe (4MB RW') per XCD pair; 32 CUs share it from L2.
__global__ __launch_bounds__(1024) void k_gemm(const u16* __restrict__ Xb,
                                               const u16* __restrict__ RWbf,
                                               const float* __restrict__ rb,
                                               const float* __restrict__ res_b,
                                               const float* __restrict__ g,
                                               float* __restrict__ Y) {
  __shared__ alignas(16) u16 As[2][256 * 64];
  __shared__ alignas(16) u16 Bs[2][256 * 64];
  int hw = blockIdx.x;
  int nt = (hw & 7) >> 1;                 // 4 col-stripes, 2 XCDs each
  int b  = (hw & 1) * 32 + (hw >> 3);     // chunk
  int t0 = b * 256, o0 = nt * 256;
  int tid = threadIdx.x, lane = tid & 63, wv = tid >> 6;   // wv 0..15
  int wr = wv >> 2, wc = wv & 3;                           // 4x4 wave grid, 64x64 each
  f32x4 acc[4][4] = {};
  const u16* aG = Xb + (size_t)t0 * 1024;
  const u16* bG = RWbf + (size_t)o0 * 1024;   // + e*1048576 per expert
  float ge[8];
#pragma unroll
  for (int e = 0; e < 8; ++e) ge[e] = g[b * 8 + e];
  // A staging (1024 thr): 2 rows/thread (srow, srow+128), 16B each
  int srow = tid >> 3;                    // 0..127
  int kcol = (tid & 7) << 3;
  // B combine (1024 thr): 2 groups/thread; rB = tid>>2 (0..255), gq = (tid&3)*2 + {0,1}
  int rB = tid >> 2;
  int gq0 = (tid & 3) * 2;
  int lr = lane & 15;
  int sx = lr & 7;
  u32x4 la[2];
#pragma unroll
  for (int iss = 0; iss < 2; ++iss) {
    int r = srow + iss * 128;
    la[iss] = *(const u32x4*)(aG + (size_t)r * 1024 + kcol);
  }
  for (int kt = 0; kt < 16; ++kt) {
    int cur = kt & 1;
    int k0 = kt << 6;
    // write prefetched A regs (swizzled col)
#pragma unroll
    for (int iss = 0; iss < 2; ++iss) {
      int r = srow + iss * 128;
      int wcl = (((tid & 7) ^ (r & 7)) << 3);
      *(u32x4*)&As[cur][r * 64 + wcl] = la[iss];
    }
    // B: combine 8 experts for 2 groups of 8 elements
#pragma unroll
    for (int qq = 0; qq < 2; ++qq) {
      int gq = gq0 + qq;
      const u16* bRow = bG + (size_t)rB * 1024 + k0 + gq * 8;
      float fa[8];
#pragma unroll
      for (int j = 0; j < 8; ++j) fa[j] = 0.f;
#pragma unroll
      for (int e = 0; e < 8; ++e) {
        u32x4 v = *(const u32x4*)(bRow + (size_t)e * 1048576);
        float w = ge[e];
#pragma unroll
        for (int h = 0; h < 4; ++h) {
          unsigned lo = v[h] << 16;
          unsigned hi = v[h] & 0xFFFF0000u;
          fa[2 * h]     += w * __builtin_bit_cast(float, lo);
          fa[2 * h + 1] += w * __builtin_bit_cast(float, hi);
        }
      }
      u32x4 pk;
#pragma unroll
      for (int h = 0; h < 4; ++h)
        pk[h] = (unsigned)f2bf(fa[2 * h]) | ((unsigned)f2bf(fa[2 * h + 1]) << 16);
      *(u32x4*)&Bs[cur][rB * 64 + ((gq ^ (rB & 7)) << 3)] = pk;
    }
    __syncthreads();
    if (kt < 15) {
      int k0n = (kt + 1) << 6;
#pragma unroll
      for (int iss = 0; iss < 2; ++iss) {
        int r = srow + iss * 128;
        la[iss] = *(const u32x4*)(aG + (size_t)r * 1024 + k0n + kcol);
      }
    }
#pragma unroll
    for (int kk = 0; kk < 2; ++kk) {
      int c16 = kk * 4 + (lane >> 4);
      int cp = ((c16 ^ sx) << 3);
      bf16x8 af[4], bfr[4];
#pragma unroll
      for (int mi = 0; mi < 4; ++mi)
        af[mi] = *(const bf16x8*)&As[cur][(wr * 64 + mi * 16 + lr) * 64 + cp];
#pragma unroll
      for (int ni = 0; ni < 4; ++ni)
        bfr[ni] = *(const bf16x8*)&Bs[cur][(wc * 64 + ni * 16 + lr) * 64 + cp];
#pragma unroll
      for (int mi = 0; mi < 4; ++mi)
#pragma unroll
        for (int ni = 0; ni < 4; ++ni)
          acc[mi][ni] = __builtin_amdgcn_mfma_f32_16x16x32_bf16(af[mi], bfr[ni], acc[mi][ni], 0, 0, 0);
    }
    // single barrier per iter (validated R10/R11): iter k+2's buf-writes are ordered
    // after barrier k+1, which laggards release only after their iter-k reads.
  }
  int rbase = (lane >> 4) << 2;
#pragma unroll
  for (int ni = 0; ni < 4; ++ni) {
    int o = o0 + wc * 64 + ni * 16 + lr;
    float ebv = res_b[o];
#pragma unroll
    for (int e = 0; e < 8; ++e) ebv += ge[e] * rb[e * 1024 + o];
#pragma unroll
    for (int mi = 0; mi < 4; ++mi) {
      int trow = t0 + wr * 64 + mi * 16 + rbase;
      float* yp = Y + (size_t)trow * 1024 + o;
      yp[0]    = acc[mi][ni][0] + ebv;
      yp[1024] = acc[mi][ni][1] + ebv;
      yp[2048] = acc[mi][ni][2] + ebv;
      yp[3072] = acc[mi][ni][3] + ebv;
    }
  }
}

extern "C" void kernel_launch(void* const* d_in, const int* in_sizes, int n_in,
                              void* d_out, int out_size, void* d_ws, size_t ws_size,
                              hipStream_t stream) {
  const float* x      = (const float*)d_in[0];
  const float* w_gate = (const float*)d_in[1];
  const float* weight = (const float*)d_in[2];
  const float* bias   = (const float*)d_in[3];
  const float* res_w  = (const float*)d_in[4];
  const float* res_b  = (const float*)d_in[5];
  const float* c1i    = (const float*)d_in[6];
  const float* c2i    = (const float*)d_in[7];
  const float* c1o    = (const float*)d_in[8];
  const float* c2o    = (const float*)d_in[9];
  const float* c1b    = (const float*)d_in[10];
  const float* c2b    = (const float*)d_in[11];
  float* y = (float*)d_out;

  if (ws_size < WS_NEED) return;

  char* wsb = (char*)d_ws;
  u16*   xbf   = (u16*)(wsb + OFF_XBF);
  u16*   T2t   = (u16*)(wsb + OFF_T2);
  float* pm    = (float*)(wsb + OFF_PM);
  u16*   RWbf  = (u16*)(wsb + OFF_RW);
  float* lgts  = (float*)(wsb + OFF_LG);
  float* g     = (float*)(wsb + OFF_G);
  float* rb    = (float*)(wsb + OFF_RB);

  k_means    <<<dim3(64, 16), 256, 0, stream>>>(x, pm, xbf);
  k_redlogits<<<64, 256, 0, stream>>>(pm, w_gate, lgts);
  k_mergeA   <<<dim3(129, 8), 256, 0, stream>>>(weight, res_w, c1o, c2o, T2t,
                                                bias, res_b, c1b, c2b, rb);
  k_mergeB   <<<dim3(129, 8), 256, 0, stream>>>(T2t, c1i, c2i, res_w, RWbf,
                                                lgts, g, y + 16777216);
  k_gemm     <<<256, 1024, 0, stream>>>(xbf, RWbf, rb, res_b, g, y);
}

// Round 14
// 240.993 us; speedup vs baseline: 1.3196x; 1.2168x over previous
//
#include <hip/hip_runtime.h>
#include <cstdint>

typedef __bf16 bf16x8 __attribute__((ext_vector_type(8)));
typedef float  f32x4  __attribute__((ext_vector_type(4)));
typedef unsigned int u32x4 __attribute__((ext_vector_type(4)));
using u16 = unsigned short;

struct alignas(8) u16x4 { u16 x, y, z, w; };

__device__ __forceinline__ u16 f2bf(float f) {
  unsigned u = __builtin_bit_cast(unsigned, f);
  u = (u + 0x7FFFu + ((u >> 16) & 1u)) >> 16;   // RNE; inputs finite
  return (u16)u;
}
__device__ __forceinline__ float bf2f(u16 u) {
  unsigned v = ((unsigned)u) << 16;
  return __builtin_bit_cast(float, v);
}

#define ASYNC16(gp, lp) __builtin_amdgcn_global_load_lds( \
    (__attribute__((address_space(1))) void*)(void*)(gp),  \
    (__attribute__((address_space(3))) void*)(lp), 16, 0, 0)

// ---------------- ws layout (bytes) ----------------
static constexpr size_t OFF_XBF  = 0;
static constexpr size_t OFF_T2   = 33554432;       // bf16 (16 MB)
static constexpr size_t OFF_PM   = 67108864;       // means partials, 4 MB
static constexpr size_t OFF_RW   = 167772160;      // bf16 RW' = RW + R (16 MB)
static constexpr size_t OFF_LG   = 201326592;      // logits [64][8]
static constexpr size_t OFF_G    = 201588736;
static constexpr size_t OFF_RB   = 201592832;
static constexpr size_t WS_NEED  = 201887744;

// ---------- chunk means (16-row segments) + x -> bf16, float4 vectorized ----------
__global__ __launch_bounds__(256) void k_means(const float* __restrict__ x,
                                               float* __restrict__ pm,
                                               u16* __restrict__ xbf) {
  int b = blockIdx.x, q = blockIdx.y, tid = threadIdx.x;
  const float* xb = x + (size_t)b * 262144 + (size_t)q * 16384 + tid * 4;
  u16* xo = xbf + (size_t)b * 262144 + (size_t)q * 16384 + tid * 4;
  float s0 = 0.f, s1 = 0.f, s2 = 0.f, s3 = 0.f;
#pragma unroll
  for (int t = 0; t < 16; ++t) {
    float4 v = *(const float4*)(xb + t * 1024);
    s0 += v.x; s1 += v.y; s2 += v.z; s3 += v.w;
    u16x4 o; o.x = f2bf(v.x); o.y = f2bf(v.y); o.z = f2bf(v.z); o.w = f2bf(v.w);
    *(u16x4*)(xo + t * 1024) = o;
  }
  float4 sv; sv.x = s0; sv.y = s1; sv.z = s2; sv.w = s3;
  *(float4*)(pm + ((size_t)b * 16 + q) * 1024 + tid * 4) = sv;
}

// ---------- reduce partial means + logits GEMV ----------
__global__ __launch_bounds__(256) void k_redlogits(const float* __restrict__ pm,
                                                   const float* __restrict__ w_gate,
                                                   float* __restrict__ logits) {
  __shared__ float red[4][8];
  int b = blockIdx.x, tid = threadIdx.x;
  const float* p = pm + (size_t)b * 16384 + tid * 4;
  float4 s = {0.f, 0.f, 0.f, 0.f};
#pragma unroll
  for (int q = 0; q < 16; ++q) {
    float4 v = *(const float4*)(p + q * 1024);
    s.x += v.x; s.y += v.y; s.z += v.z; s.w += v.w;
  }
  int i0 = tid * 4;
  float acc[8];
#pragma unroll
  for (int e = 0; e < 8; ++e) {
    acc[e] = s.x * w_gate[(i0 + 0) * 8 + e] + s.y * w_gate[(i0 + 1) * 8 + e]
           + s.z * w_gate[(i0 + 2) * 8 + e] + s.w * w_gate[(i0 + 3) * 8 + e];
  }
#pragma unroll
  for (int off = 32; off >= 1; off >>= 1)
#pragma unroll
    for (int e = 0; e < 8; ++e) acc[e] += __shfl_down(acc[e], off, 64);
  int wv = tid >> 6;
  if ((tid & 63) == 0)
#pragma unroll
    for (int e = 0; e < 8; ++e) red[wv][e] = acc[e];
  __syncthreads();
  if (tid < 8)
    logits[b * 8 + tid] =
        (red[0][tid] + red[1][tid] + red[2][tid] + red[3][tid]) * (1.f / 256.f);
}

// ---------- mergeA (+rb tail at bx==128): T2t[e][lm][o] (bf16) ----------
__global__ __launch_bounds__(256) void k_mergeA(const float* __restrict__ W,
                                                const float* __restrict__ R,
                                                const float* __restrict__ c1o,
                                                const float* __restrict__ c2o,
                                                u16* __restrict__ T2t,
                                                const float* __restrict__ bias,
                                                const float* __restrict__ res_bias,
                                                const float* __restrict__ c1b,
                                                const float* __restrict__ c2b,
                                                float* __restrict__ rb) {
  int e = blockIdx.y, bx = blockIdx.x, tid = threadIdx.x;
  if (bx == 128) {
    __shared__ float rb0[32][33], rb1[32][33], m1b[32][32], m2b[32][32];
    for (int idx = tid; idx < 1024; idx += 256) {
      int i = idx >> 5, j = idx & 31;
      rb0[i][j] = bias[e * 1024 + idx] - res_bias[idx];
      m1b[i][j] = c1b[e * 1024 + idx];
      m2b[i][j] = c2b[e * 1024 + idx];
    }
    __syncthreads();
    for (int idx = tid; idx < 1024; idx += 256) {
      int p = idx >> 5, j = idx & 31;
      float s = 0.f;
#pragma unroll
      for (int i = 0; i < 32; ++i) s += m1b[p][i] * rb0[i][j];
      rb1[p][j] = s;
    }
    __syncthreads();
    for (int idx = tid; idx < 1024; idx += 256) {
      int p = idx >> 5, q = idx & 31;
      float s = 0.f;
#pragma unroll
      for (int j = 0; j < 32; ++j) s += m2b[q][j] * rb1[p][j];
      rb[e * 1024 + idx] = s;
    }
    return;
  }
  __shared__ float dw[8 * 1024];        // [c][jk]
  __shared__ float m1[1024], m2[1024];
  int c0 = bx * 8;
  const float* We = W + (size_t)e * 1048576;
  for (int idx = tid; idx < 1024; idx += 256) {
    m1[idx] = c1o[e * 1024 + idx];
    m2[idx] = c2o[e * 1024 + idx];
  }
  {
    int r = tid >> 1, h = (tid & 1) * 4;
#pragma unroll
    for (int i = 0; i < 8; ++i) {
      int row = r + i * 128;
      const float4 wv = *(const float4*)(We + (size_t)row * 1024 + c0 + h);
      const float4 rv = *(const float4*)(R + (size_t)row * 1024 + c0 + h);
      dw[(h + 0) * 1024 + row] = wv.x - rv.x;
      dw[(h + 1) * 1024 + row] = wv.y - rv.y;
      dw[(h + 2) * 1024 + row] = wv.z - rv.z;
      dw[(h + 3) * 1024 + row] = wv.w - rv.w;
    }
  }
  __syncthreads();
  int i1 = tid & 31, c = tid >> 5;
  const float* dwc = dw + c * 1024;
  float U[32];
#pragma unroll
  for (int k = 0; k < 32; ++k) U[k] = 0.f;
  for (int j = 0; j < 32; ++j) {
    float cj = m1[i1 * 32 + j];
    const float4* rowp = (const float4*)(dwc + j * 32);
#pragma unroll
    for (int k4 = 0; k4 < 8; ++k4) {
      float4 v = rowp[k4];
      U[k4 * 4 + 0] += cj * v.x; U[k4 * 4 + 1] += cj * v.y;
      U[k4 * 4 + 2] += cj * v.z; U[k4 * 4 + 3] += cj * v.w;
    }
  }
  u16* obase = T2t + (size_t)e * 1048576 + (size_t)(c0 + c) * 1024 + i1 * 32;
#pragma unroll
  for (int g4 = 0; g4 < 8; ++g4) {
    float s[4];
#pragma unroll
    for (int q = 0; q < 4; ++q) {
      const float4* m2r = (const float4*)(m2 + (g4 * 4 + q) * 32);
      float acc = 0.f;
#pragma unroll
      for (int k4 = 0; k4 < 8; ++k4) {
        float4 mv = m2r[k4];
        acc += mv.x * U[k4 * 4 + 0] + mv.y * U[k4 * 4 + 1]
             + mv.z * U[k4 * 4 + 2] + mv.w * U[k4 * 4 + 3];
      }
      s[q] = acc;
    }
    u16x4 o4; o4.x = f2bf(s[0]); o4.y = f2bf(s[1]); o4.z = f2bf(s[2]); o4.w = f2bf(s[3]);
    *(u16x4*)(obase + g4 * 4) = o4;
  }
}

// ---------- mergeB (+gatefin tail): RW'[e][o][i] = bf16( R[o][i] + sum C1i C2i T2t ) ----------
__global__ __launch_bounds__(256) void k_mergeB(const u16* __restrict__ T2t,
                                                const float* __restrict__ c1i,
                                                const float* __restrict__ c2i,
                                                const float* __restrict__ R,
                                                u16* __restrict__ RWbf,
                                                const float* __restrict__ logits,
                                                float* __restrict__ g,
                                                float* __restrict__ loss_out) {
  int e = blockIdx.y, bx = blockIdx.x, tid = threadIdx.x;
  if (bx == 128) {
    if (e != 0) return;
    __shared__ float gates[64][8];
    __shared__ float imp[8];
    if (tid < 64) {
      float lg[8];
#pragma unroll
      for (int j = 0; j < 8; ++j) lg[j] = logits[tid * 8 + j];
      float mx = lg[0];
#pragma unroll
      for (int j = 1; j < 8; ++j) mx = fmaxf(mx, lg[j]);
      float s = 0.f, ex[8];
#pragma unroll
      for (int j = 0; j < 8; ++j) { ex[j] = expf(lg[j] - mx); s += ex[j]; }
      float inv = 1.f / s;
#pragma unroll
      for (int j = 0; j < 8; ++j) gates[tid][j] = ex[j] * inv;
    }
    __syncthreads();
    if (tid < 8) {
      float s = 0.f;
      for (int bb = 0; bb < 64; ++bb) s += gates[bb][tid];
      imp[tid] = s;
    }
    __syncthreads();
    if (tid == 0) {
      float mean = 0.f;
#pragma unroll
      for (int j = 0; j < 8; ++j) mean += imp[j];
      mean *= (1.f / 8.f);
      float var = 0.f;
#pragma unroll
      for (int j = 0; j < 8; ++j) { float d = imp[j] - mean; var += d * d; }
      var *= (1.f / 7.f);                         // ddof=1
      loss_out[0] = (var / (mean * mean + 1e-10f)) * 1e-5f;
    }
    __syncthreads();
    if (tid < 64) {
      int src = ((tid & 7) == 0) ? tid : tid - 1; // roll by one chunk, keep first
#pragma unroll
      for (int j = 0; j < 8; ++j) g[tid * 8 + j] = gates[src][j];
    }
    return;
  }
  __shared__ float t2[8 * 1024];        // [oc][lm]
  __shared__ float m1[1024], m2[1024];
  int o0 = bx * 8;
  const u16* Te = T2t + (size_t)e * 1048576;
  for (int idx = tid; idx < 1024; idx += 256) {
    m1[idx] = c1i[e * 1024 + idx];
    m2[idx] = c2i[e * 1024 + idx];
  }
  {
    int r = tid >> 1, h = (tid & 1) * 4;
#pragma unroll
    for (int i = 0; i < 8; ++i) {
      int row = r + i * 128;
      const u16x4 tv = *(const u16x4*)(Te + (size_t)row * 1024 + o0 + h);
      t2[(h + 0) * 1024 + row] = bf2f(tv.x);
      t2[(h + 1) * 1024 + row] = bf2f(tv.y);
      t2[(h + 2) * 1024 + row] = bf2f(tv.z);
      t2[(h + 3) * 1024 + row] = bf2f(tv.w);
    }
  }
  __syncthreads();
  int i1 = tid & 31, oc = tid >> 5;
  const float* t2c = t2 + oc * 1024;
  float A[32];
#pragma unroll
  for (int m = 0; m < 32; ++m) A[m] = 0.f;
  for (int l = 0; l < 32; ++l) {
    float cl = m1[i1 * 32 + l];
    const float4* rowp = (const float4*)(t2c + l * 32);
#pragma unroll
    for (int m4 = 0; m4 < 8; ++m4) {
      float4 v = rowp[m4];
      A[m4 * 4 + 0] += cl * v.x; A[m4 * 4 + 1] += cl * v.y;
      A[m4 * 4 + 2] += cl * v.z; A[m4 * 4 + 3] += cl * v.w;
    }
  }
  const float* Rrow = R + (size_t)(o0 + oc) * 1024 + i1 * 32;
  u16* obase = RWbf + ((size_t)e * 1024 + o0 + oc) * 1024 + i1 * 32;
#pragma unroll
  for (int g4 = 0; g4 < 8; ++g4) {
    float s[4];
#pragma unroll
    for (int q = 0; q < 4; ++q) {
      const float4* m2r = (const float4*)(m2 + (g4 * 4 + q) * 32);
      float acc = Rrow[g4 * 4 + q];               // fold residual: RW' = R + merged
#pragma unroll
      for (int m4 = 0; m4 < 8; ++m4) {
        float4 mv = m2r[m4];
        acc += mv.x * A[m4 * 4 + 0] + mv.y * A[m4 * 4 + 1]
             + mv.z * A[m4 * 4 + 2] + mv.w * A[m4 * 4 + 3];
      }
      s[q] = acc;
    }
    u16x4 o4; o4.x = f2bf(s[0]); o4.y = f2bf(s[1]); o4.z = f2bf(s[2]); o4.w = f2bf(s[3]);
    *(u16x4*)(obase + g4 * 4) = o4;
  }
}

// ---------- fused GEMM, design C: BM=256 x BN=128, 512 thr, 8 waves, 2 blocks/CU ----------
// Register budget (128 unified @ 4 waves/SIMD): acc 64 + af/bfr 32 + combine ~16 + addr ~10.
// A via ASYNC16 (pre-swizzled source, zero reg cost). B = sum_e ge*RW'[e] combined on the
// fly from L2-resident stripes. XCD 2x4 map: chunk-half x stripe-pair.
__global__ __launch_bounds__(512) void k_gemm(const u16* __restrict__ Xb,
                                              const u16* __restrict__ RWbf,
                                              const float* __restrict__ rb,
                                              const float* __restrict__ res_b,
                                              const float* __restrict__ g,
                                              float* __restrict__ Y) {
  __shared__ alignas(16) u16 As[256 * 64];
  __shared__ alignas(16) u16 Bs[128 * 64];
  int hw = blockIdx.x;                   // 0..511
  int xcd = hw & 7;
  int half = xcd >> 2;                   // chunk half   (0..1)
  int jj   = xcd & 3;                    // stripe pair  (0..3)
  int w    = hw >> 3;                    // 0..63
  int b  = half * 32 + (w >> 1);
  int nt = jj * 2 + (w & 1);             // 0..7 (BN=128 stripes)
  int t0 = b * 256, o0 = nt * 128;
  int tid = threadIdx.x, lane = tid & 63, wv = tid >> 6;
  int wr = wv >> 1, wc = wv & 1;         // 4M x 2N waves, 64x64 each
  f32x4 acc[4][4] = {};
  const u16* aG = Xb + (size_t)t0 * 1024;
  const u16* bG = RWbf + (size_t)o0 * 1024;
  float ge[8];
#pragma unroll
  for (int e = 0; e < 8; ++e)
    ge[e] = __builtin_bit_cast(float, __builtin_amdgcn_readfirstlane(
                __builtin_bit_cast(int, g[b * 8 + e])));
  // A staging: 4x ASYNC16, rows srow+iss*64, pre-swizzled global col
  int srow = tid >> 3;
  int scol = (tid & 7) << 3;
  int gcol = (((tid & 7) ^ (srow & 7)) << 3);
  // B combine: rB = tid>>2 (0..127), 2 groups gq0+{0,1}
  int rB = tid >> 2;
  int gq0 = (tid & 3) * 2;
  int lr = lane & 15;
  int sx = lr & 7;
  for (int kt = 0; kt < 16; ++kt) {
    int k0 = kt << 6;
#pragma unroll
    for (int iss = 0; iss < 4; ++iss) {
      int r = srow + iss * 64;
      ASYNC16(aG + (size_t)r * 1024 + k0 + gcol, &As[r * 64 + scol]);
    }
#pragma unroll
    for (int qq = 0; qq < 2; ++qq) {
      int gq = gq0 + qq;
      const u16* bRow = bG + (size_t)rB * 1024 + k0 + gq * 8;
      float fa[8];
#pragma unroll
      for (int jx = 0; jx < 8; ++jx) fa[jx] = 0.f;
#pragma unroll
      for (int e = 0; e < 8; ++e) {
        u32x4 v = *(const u32x4*)(bRow + (size_t)e * 1048576);
        float wght = ge[e];
#pragma unroll
        for (int h = 0; h < 4; ++h) {
          unsigned lo = v[h] << 16;
          unsigned hi = v[h] & 0xFFFF0000u;
          fa[2 * h]     += wght * __builtin_bit_cast(float, lo);
          fa[2 * h + 1] += wght * __builtin_bit_cast(float, hi);
        }
      }
      u32x4 pk;
#pragma unroll
      for (int h = 0; h < 4; ++h)
        pk[h] = (unsigned)f2bf(fa[2 * h]) | ((unsigned)f2bf(fa[2 * h + 1]) << 16);
      *(u32x4*)&Bs[rB * 64 + ((gq ^ (rB & 7)) << 3)] = pk;
    }
    __syncthreads();   // drains A ASYNC16 + orders B ds_writes
#pragma unroll
    for (int kk = 0; kk < 2; ++kk) {
      int c16 = kk * 4 + (lane >> 4);
      int cp = ((c16 ^ sx) << 3);
      bf16x8 af[4], bfr[4];
#pragma unroll
      for (int mi = 0; mi < 4; ++mi)
        af[mi] = *(const bf16x8*)&As[(wr * 64 + mi * 16 + lr) * 64 + cp];
#pragma unroll
      for (int ni = 0; ni < 4; ++ni)
        bfr[ni] = *(const bf16x8*)&Bs[(wc * 64 + ni * 16 + lr) * 64 + cp];
#pragma unroll
      for (int mi = 0; mi < 4; ++mi)
#pragma unroll
        for (int ni = 0; ni < 4; ++ni)
          acc[mi][ni] = __builtin_amdgcn_mfma_f32_16x16x32_bf16(af[mi], bfr[ni], acc[mi][ni], 0, 0, 0);
    }
    __syncthreads();   // protect single buffers before next-iter overwrite
  }
  int rbase = (lane >> 4) << 2;
#pragma unroll
  for (int ni = 0; ni < 4; ++ni) {
    int o = o0 + wc * 64 + ni * 16 + lr;
    float ebv = res_b[o];
#pragma unroll
    for (int e = 0; e < 8; ++e) ebv += ge[e] * rb[e * 1024 + o];
#pragma unroll
    for (int mi = 0; mi < 4; ++mi) {
      int trow = t0 + wr * 64 + mi * 16 + rbase;
      float* yp = Y + (size_t)trow * 1024 + o;
      yp[0]    = acc[mi][ni][0] + ebv;
      yp[1024] = acc[mi][ni][1] + ebv;
      yp[2048] = acc[mi][ni][2] + ebv;
      yp[3072] = acc[mi][ni][3] + ebv;
    }
  }
}

extern "C" void kernel_launch(void* const* d_in, const int* in_sizes, int n_in,
                              void* d_out, int out_size, void* d_ws, size_t ws_size,
                              hipStream_t stream) {
  const float* x      = (const float*)d_in[0];
  const float* w_gate = (const float*)d_in[1];
  const float* weight = (const float*)d_in[2];
  const float* bias   = (const float*)d_in[3];
  const float* res_w  = (const float*)d_in[4];
  const float* res_b  = (const float*)d_in[5];
  const float* c1i    = (const float*)d_in[6];
  const float* c2i    = (const float*)d_in[7];
  const float* c1o    = (const float*)d_in[8];
  const float* c2o    = (const float*)d_in[9];
  const float* c1b    = (const float*)d_in[10];
  const float* c2b    = (const float*)d_in[11];
  float* y = (float*)d_out;

  if (ws_size < WS_NEED) return;

  char* wsb = (char*)d_ws;
  u16*   xbf   = (u16*)(wsb + OFF_XBF);
  u16*   T2t   = (u16*)(wsb + OFF_T2);
  float* pm    = (float*)(wsb + OFF_PM);
  u16*   RWbf  = (u16*)(wsb + OFF_RW);
  float* lgts  = (float*)(wsb + OFF_LG);
  float* g     = (float*)(wsb + OFF_G);
  float* rb    = (float*)(wsb + OFF_RB);

  k_means    <<<dim3(64, 16), 256, 0, stream>>>(x, pm, xbf);
  k_redlogits<<<64, 256, 0, stream>>>(pm, w_gate, lgts);
  k_mergeA   <<<dim3(129, 8), 256, 0, stream>>>(weight, res_w, c1o, c2o, T2t,
                                                bias, res_b, c1b, c2b, rb);
  k_mergeB   <<<dim3(129, 8), 256, 0, stream>>>(T2t, c1i, c2i, res_w, RWbf,
                                                lgts, g, y + 16777216);
  k_gemm     <<<512, 512, 0, stream>>>(xbf, RWbf, rb, res_b, g, y);
}

// Round 15
// 205.439 us; speedup vs baseline: 1.5479x; 1.1731x over previous
//
#include <hip/hip_runtime.h>
#include <cstdint>

typedef __bf16 bf16x8 __attribute__((ext_vector_type(8)));
typedef float  f32x4  __attribute__((ext_vector_type(4)));
typedef unsigned int u32x4 __attribute__((ext_vector_type(4)));
using u16 = unsigned short;

struct alignas(8) u16x4 { u16 x, y, z, w; };

__device__ __forceinline__ u16 f2bf(float f) {
  unsigned u = __builtin_bit_cast(unsigned, f);
  u = (u + 0x7FFFu + ((u >> 16) & 1u)) >> 16;   // RNE; inputs finite
  return (u16)u;
}
__device__ __forceinline__ float bf2f(u16 u) {
  unsigned v = ((unsigned)u) << 16;
  return __builtin_bit_cast(float, v);
}

// ---------------- ws layout (bytes) ----------------
static constexpr size_t OFF_XBF  = 0;
static constexpr size_t OFF_EW   = 33554432;       // bf16 EW [64][1024][1024] (128 MB)
static constexpr size_t OFF_T2   = 33554432;       // alias: dead before combine writes EW
static constexpr size_t OFF_PM   = 67108864;       // alias: dead before combine
static constexpr size_t OFF_RW   = 167772160;      // bf16 RW' = R + rw (16 MB)
static constexpr size_t OFF_LG   = 201326592;
static constexpr size_t OFF_G    = 201588736;
static constexpr size_t OFF_RB   = 201592832;
static constexpr size_t WS_NEED  = 201887744;

// ---------- chunk means (16-row segments) + x -> bf16, float4 vectorized ----------
__global__ __launch_bounds__(256) void k_means(const float* __restrict__ x,
                                               float* __restrict__ pm,
                                               u16* __restrict__ xbf) {
  int b = blockIdx.x, q = blockIdx.y, tid = threadIdx.x;
  const float* xb = x + (size_t)b * 262144 + (size_t)q * 16384 + tid * 4;
  u16* xo = xbf + (size_t)b * 262144 + (size_t)q * 16384 + tid * 4;
  float s0 = 0.f, s1 = 0.f, s2 = 0.f, s3 = 0.f;
#pragma unroll
  for (int t = 0; t < 16; ++t) {
    float4 v = *(const float4*)(xb + t * 1024);
    s0 += v.x; s1 += v.y; s2 += v.z; s3 += v.w;
    u16x4 o; o.x = f2bf(v.x); o.y = f2bf(v.y); o.z = f2bf(v.z); o.w = f2bf(v.w);
    *(u16x4*)(xo + t * 1024) = o;
  }
  float4 sv; sv.x = s0; sv.y = s1; sv.z = s2; sv.w = s3;
  *(float4*)(pm + ((size_t)b * 16 + q) * 1024 + tid * 4) = sv;
}

// ---------- reduce partial means + logits GEMV ----------
__global__ __launch_bounds__(256) void k_redlogits(const float* __restrict__ pm,
                                                   const float* __restrict__ w_gate,
                                                   float* __restrict__ logits) {
  __shared__ float red[4][8];
  int b = blockIdx.x, tid = threadIdx.x;
  const float* p = pm + (size_t)b * 16384 + tid * 4;
  float4 s = {0.f, 0.f, 0.f, 0.f};
#pragma unroll
  for (int q = 0; q < 16; ++q) {
    float4 v = *(const float4*)(p + q * 1024);
    s.x += v.x; s.y += v.y; s.z += v.z; s.w += v.w;
  }
  int i0 = tid * 4;
  float acc[8];
#pragma unroll
  for (int e = 0; e < 8; ++e) {
    acc[e] = s.x * w_gate[(i0 + 0) * 8 + e] + s.y * w_gate[(i0 + 1) * 8 + e]
           + s.z * w_gate[(i0 + 2) * 8 + e] + s.w * w_gate[(i0 + 3) * 8 + e];
  }
#pragma unroll
  for (int off = 32; off >= 1; off >>= 1)
#pragma unroll
    for (int e = 0; e < 8; ++e) acc[e] += __shfl_down(acc[e], off, 64);
  int wv = tid >> 6;
  if ((tid & 63) == 0)
#pragma unroll
    for (int e = 0; e < 8; ++e) red[wv][e] = acc[e];
  __syncthreads();
  if (tid < 8)
    logits[b * 8 + tid] =
        (red[0][tid] + red[1][tid] + red[2][tid] + red[3][tid]) * (1.f / 256.f);
}

// ---------- mergeA (+rb tail at bx==128): T2t[e][lm][o] (bf16) ----------
__global__ __launch_bounds__(256) void k_mergeA(const float* __restrict__ W,
                                                const float* __restrict__ R,
                                                const float* __restrict__ c1o,
                                                const float* __restrict__ c2o,
                                                u16* __restrict__ T2t,
                                                const float* __restrict__ bias,
                                                const float* __restrict__ res_bias,
                                                const float* __restrict__ c1b,
                                                const float* __restrict__ c2b,
                                                float* __restrict__ rb) {
  int e = blockIdx.y, bx = blockIdx.x, tid = threadIdx.x;
  if (bx == 128) {
    __shared__ float rb0[32][33], rb1[32][33], m1b[32][32], m2b[32][32];
    for (int idx = tid; idx < 1024; idx += 256) {
      int i = idx >> 5, j = idx & 31;
      rb0[i][j] = bias[e * 1024 + idx] - res_bias[idx];
      m1b[i][j] = c1b[e * 1024 + idx];
      m2b[i][j] = c2b[e * 1024 + idx];
    }
    __syncthreads();
    for (int idx = tid; idx < 1024; idx += 256) {
      int p = idx >> 5, j = idx & 31;
      float s = 0.f;
#pragma unroll
      for (int i = 0; i < 32; ++i) s += m1b[p][i] * rb0[i][j];
      rb1[p][j] = s;
    }
    __syncthreads();
    for (int idx = tid; idx < 1024; idx += 256) {
      int p = idx >> 5, q = idx & 31;
      float s = 0.f;
#pragma unroll
      for (int j = 0; j < 32; ++j) s += m2b[q][j] * rb1[p][j];
      rb[e * 1024 + idx] = s;
    }
    return;
  }
  __shared__ float dw[8 * 1024];        // [c][jk]
  __shared__ float m1[1024], m2[1024];
  int c0 = bx * 8;
  const float* We = W + (size_t)e * 1048576;
  for (int idx = tid; idx < 1024; idx += 256) {
    m1[idx] = c1o[e * 1024 + idx];
    m2[idx] = c2o[e * 1024 + idx];
  }
  {
    int r = tid >> 1, h = (tid & 1) * 4;
#pragma unroll
    for (int i = 0; i < 8; ++i) {
      int row = r + i * 128;
      const float4 wv = *(const float4*)(We + (size_t)row * 1024 + c0 + h);
      const float4 rv = *(const float4*)(R + (size_t)row * 1024 + c0 + h);
      dw[(h + 0) * 1024 + row] = wv.x - rv.x;
      dw[(h + 1) * 1024 + row] = wv.y - rv.y;
      dw[(h + 2) * 1024 + row] = wv.z - rv.z;
      dw[(h + 3) * 1024 + row] = wv.w - rv.w;
    }
  }
  __syncthreads();
  int i1 = tid & 31, c = tid >> 5;
  const float* dwc = dw + c * 1024;
  float U[32];
#pragma unroll
  for (int k = 0; k < 32; ++k) U[k] = 0.f;
  for (int j = 0; j < 32; ++j) {
    float cj = m1[i1 * 32 + j];
    const float4* rowp = (const float4*)(dwc + j * 32);
#pragma unroll
    for (int k4 = 0; k4 < 8; ++k4) {
      float4 v = rowp[k4];
      U[k4 * 4 + 0] += cj * v.x; U[k4 * 4 + 1] += cj * v.y;
      U[k4 * 4 + 2] += cj * v.z; U[k4 * 4 + 3] += cj * v.w;
    }
  }
  u16* obase = T2t + (size_t)e * 1048576 + (size_t)(c0 + c) * 1024 + i1 * 32;
#pragma unroll
  for (int g4 = 0; g4 < 8; ++g4) {
    float s[4];
#pragma unroll
    for (int q = 0; q < 4; ++q) {
      const float4* m2r = (const float4*)(m2 + (g4 * 4 + q) * 32);
      float acc = 0.f;
#pragma unroll
      for (int k4 = 0; k4 < 8; ++k4) {
        float4 mv = m2r[k4];
        acc += mv.x * U[k4 * 4 + 0] + mv.y * U[k4 * 4 + 1]
             + mv.z * U[k4 * 4 + 2] + mv.w * U[k4 * 4 + 3];
      }
      s[q] = acc;
    }
    u16x4 o4; o4.x = f2bf(s[0]); o4.y = f2bf(s[1]); o4.z = f2bf(s[2]); o4.w = f2bf(s[3]);
    *(u16x4*)(obase + g4 * 4) = o4;
  }
}

// ---------- mergeB (+gatefin tail): RW'[e][o][i] = bf16( R[o][i] + sum C1i C2i T2t ) ----------
__global__ __launch_bounds__(256) void k_mergeB(const u16* __restrict__ T2t,
                                                const float* __restrict__ c1i,
                                                const float* __restrict__ c2i,
                                                const float* __restrict__ R,
                                                u16* __restrict__ RWbf,
                                                const float* __restrict__ logits,
                                                float* __restrict__ g,
                                                float* __restrict__ loss_out) {
  int e = blockIdx.y, bx = blockIdx.x, tid = threadIdx.x;
  if (bx == 128) {
    if (e != 0) return;
    __shared__ float gates[64][8];
    __shared__ float imp[8];
    if (tid < 64) {
      float lg[8];
#pragma unroll
      for (int j = 0; j < 8; ++j) lg[j] = logits[tid * 8 + j];
      float mx = lg[0];
#pragma unroll
      for (int j = 1; j < 8; ++j) mx = fmaxf(mx, lg[j]);
      float s = 0.f, ex[8];
#pragma unroll
      for (int j = 0; j < 8; ++j) { ex[j] = expf(lg[j] - mx); s += ex[j]; }
      float inv = 1.f / s;
#pragma unroll
      for (int j = 0; j < 8; ++j) gates[tid][j] = ex[j] * inv;
    }
    __syncthreads();
    if (tid < 8) {
      float s = 0.f;
      for (int bb = 0; bb < 64; ++bb) s += gates[bb][tid];
      imp[tid] = s;
    }
    __syncthreads();
    if (tid == 0) {
      float mean = 0.f;
#pragma unroll
      for (int j = 0; j < 8; ++j) mean += imp[j];
      mean *= (1.f / 8.f);
      float var = 0.f;
#pragma unroll
      for (int j = 0; j < 8; ++j) { float d = imp[j] - mean; var += d * d; }
      var *= (1.f / 7.f);                         // ddof=1
      loss_out[0] = (var / (mean * mean + 1e-10f)) * 1e-5f;
    }
    __syncthreads();
    if (tid < 64) {
      int src = ((tid & 7) == 0) ? tid : tid - 1; // roll by one chunk, keep first
#pragma unroll
      for (int j = 0; j < 8; ++j) g[tid * 8 + j] = gates[src][j];
    }
    return;
  }
  __shared__ float t2[8 * 1024];        // [oc][lm]
  __shared__ float m1[1024], m2[1024];
  int o0 = bx * 8;
  const u16* Te = T2t + (size_t)e * 1048576;
  for (int idx = tid; idx < 1024; idx += 256) {
    m1[idx] = c1i[e * 1024 + idx];
    m2[idx] = c2i[e * 1024 + idx];
  }
  {
    int r = tid >> 1, h = (tid & 1) * 4;
#pragma unroll
    for (int i = 0; i < 8; ++i) {
      int row = r + i * 128;
      const u16x4 tv = *(const u16x4*)(Te + (size_t)row * 1024 + o0 + h);
      t2[(h + 0) * 1024 + row] = bf2f(tv.x);
      t2[(h + 1) * 1024 + row] = bf2f(tv.y);
      t2[(h + 2) * 1024 + row] = bf2f(tv.z);
      t2[(h + 3) * 1024 + row] = bf2f(tv.w);
    }
  }
  __syncthreads();
  int i1 = tid & 31, oc = tid >> 5;
  const float* t2c = t2 + oc * 1024;
  float A[32];
#pragma unroll
  for (int m = 0; m < 32; ++m) A[m] = 0.f;
  for (int l = 0; l < 32; ++l) {
    float cl = m1[i1 * 32 + l];
    const float4* rowp = (const float4*)(t2c + l * 32);
#pragma unroll
    for (int m4 = 0; m4 < 8; ++m4) {
      float4 v = rowp[m4];
      A[m4 * 4 + 0] += cl * v.x; A[m4 * 4 + 1] += cl * v.y;
      A[m4 * 4 + 2] += cl * v.z; A[m4 * 4 + 3] += cl * v.w;
    }
  }
  const float* Rrow = R + (size_t)(o0 + oc) * 1024 + i1 * 32;
  u16* obase = RWbf + ((size_t)e * 1024 + o0 + oc) * 1024 + i1 * 32;
#pragma unroll
  for (int g4 = 0; g4 < 8; ++g4) {
    float s[4];
#pragma unroll
    for (int q = 0; q < 4; ++q) {
      const float4* m2r = (const float4*)(m2 + (g4 * 4 + q) * 32);
      float acc = Rrow[g4 * 4 + q];               // fold residual: RW' = R + merged
#pragma unroll
      for (int m4 = 0; m4 < 8; ++m4) {
        float4 mv = m2r[m4];
        acc += mv.x * A[m4 * 4 + 0] + mv.y * A[m4 * 4 + 1]
             + mv.z * A[m4 * 4 + 2] + mv.w * A[m4 * 4 + 3];
      }
      s[q] = acc;
    }
    u16x4 o4; o4.x = f2bf(s[0]); o4.y = f2bf(s[1]); o4.z = f2bf(s[2]); o4.w = f2bf(s[3]);
    *(u16x4*)(obase + g4 * 4) = o4;
  }
}

// ---------- combine: EW[b][o][i] = bf16( sum_e g[b][e] RW'[e][o][i] )  (R pre-folded) ----------
// 512 blocks x 2 o-rows, 16B loads/stores; reads 16 MB, writes 128 MB (write-bound).
__global__ __launch_bounds__(256) void k_combine(const u16* __restrict__ RWbf,
                                                 const float* __restrict__ g,
                                                 u16* __restrict__ EW) {
  __shared__ float gs[512];
  int blk = blockIdx.x, tid = threadIdx.x;
  for (int idx = tid; idx < 512; idx += 256) gs[idx] = g[idx];
  __syncthreads();
  int o = blk * 2 + (tid >> 7);
  int i0 = (tid & 127) * 8;
  float w[8][8];
#pragma unroll
  for (int e = 0; e < 8; ++e) {
    u32x4 v = *(const u32x4*)(RWbf + (size_t)e * 1048576 + (size_t)o * 1024 + i0);
#pragma unroll
    for (int h = 0; h < 4; ++h) {
      w[e][2 * h]     = __builtin_bit_cast(float, v[h] << 16);
      w[e][2 * h + 1] = __builtin_bit_cast(float, v[h] & 0xFFFF0000u);
    }
  }
  for (int b = 0; b < 64; ++b) {
    float a[8];
#pragma unroll
    for (int j = 0; j < 8; ++j) a[j] = 0.f;
#pragma unroll
    for (int e = 0; e < 8; ++e) {
      float ge = gs[b * 8 + e];
#pragma unroll
      for (int j = 0; j < 8; ++j) a[j] += ge * w[e][j];
    }
    u32x4 pk;
#pragma unroll
    for (int h = 0; h < 4; ++h)
      pk[h] = (unsigned)f2bf(a[2 * h]) | ((unsigned)f2bf(a[2 * h + 1]) << 16);
    *(u32x4*)(EW + (size_t)b * 1048576 + (size_t)o * 1024 + i0) = pk;
  }
}

// ---------- main GEMM (R10 verbatim): 256x256, BK=64, 8 waves, reg-staged dbuf ----------
__global__ __launch_bounds__(512) void k_gemm(const u16* __restrict__ Xb,
                                              const u16* __restrict__ EW,
                                              const float* __restrict__ rb,
                                              const float* __restrict__ res_b,
                                              const float* __restrict__ g,
                                              float* __restrict__ Y) {
  __shared__ alignas(16) u16 As[2][256 * 64];
  __shared__ alignas(16) u16 Bs[2][256 * 64];
  int hw = blockIdx.x;
  int xcd = hw & 7;
  int b  = xcd * 8 + (hw >> 5);
  int nt = (hw >> 3) & 3;
  int t0 = b * 256, o0 = nt * 256;
  int tid = threadIdx.x, lane = tid & 63, wv = tid >> 6;
  int wr = wv >> 2, wc = wv & 3;
  f32x4 acc[8][4] = {};
  const u16* aG = Xb + (size_t)t0 * 1024;
  const u16* bG = EW + (size_t)b * 1048576 + (size_t)o0 * 1024;
  int srow = tid >> 3;
  int kcol = (tid & 7) << 3;
  int lr = lane & 15;
  int sx = lr & 7;
  u32x4 la[4], lb[4];
#pragma unroll
  for (int iss = 0; iss < 4; ++iss) {
    int r = srow + iss * 64;
    la[iss] = *(const u32x4*)(aG + (size_t)r * 1024 + kcol);
    lb[iss] = *(const u32x4*)(bG + (size_t)r * 1024 + kcol);
  }
  for (int kt = 0; kt < 16; ++kt) {
    int cur = kt & 1;
#pragma unroll
    for (int iss = 0; iss < 4; ++iss) {
      int r = srow + iss * 64;
      int wcl = (((tid & 7) ^ (r & 7)) << 3);
      *(u32x4*)&As[cur][r * 64 + wcl] = la[iss];
      *(u32x4*)&Bs[cur][r * 64 + wcl] = lb[iss];
    }
    __syncthreads();
    if (kt < 15) {
      int k0n = (kt + 1) << 6;
#pragma unroll
      for (int iss = 0; iss < 4; ++iss) {
        int r = srow + iss * 64;
        la[iss] = *(const u32x4*)(aG + (size_t)r * 1024 + k0n + kcol);
        lb[iss] = *(const u32x4*)(bG + (size_t)r * 1024 + k0n + kcol);
      }
    }
#pragma unroll
    for (int kk = 0; kk < 2; ++kk) {
      int c16 = kk * 4 + (lane >> 4);
      int cp = ((c16 ^ sx) << 3);
      bf16x8 af[8], bfr[4];
#pragma unroll
      for (int mi = 0; mi < 8; ++mi)
        af[mi] = *(const bf16x8*)&As[cur][(wr * 128 + mi * 16 + lr) * 64 + cp];
#pragma unroll
      for (int ni = 0; ni < 4; ++ni)
        bfr[ni] = *(const bf16x8*)&Bs[cur][(wc * 64 + ni * 16 + lr) * 64 + cp];
#pragma unroll
      for (int mi = 0; mi < 8; ++mi)
#pragma unroll
        for (int ni = 0; ni < 4; ++ni)
          acc[mi][ni] = __builtin_amdgcn_mfma_f32_16x16x32_bf16(af[mi], bfr[ni], acc[mi][ni], 0, 0, 0);
    }
    // single barrier per iter: next iteration writes buf^1; the barrier at its top
    // orders any wave's t+2 writes after laggards' t reads.
  }
  float ge[8];
#pragma unroll
  for (int e = 0; e < 8; ++e) ge[e] = g[b * 8 + e];
  int rbase = (lane >> 4) << 2;
#pragma unroll
  for (int ni = 0; ni < 4; ++ni) {
    int o = o0 + wc * 64 + ni * 16 + lr;
    float ebv = res_b[o];
#pragma unroll
    for (int e = 0; e < 8; ++e) ebv += ge[e] * rb[e * 1024 + o];
#pragma unroll
    for (int mi = 0; mi < 8; ++mi) {
      int trow = t0 + wr * 128 + mi * 16 + rbase;
      float* yp = Y + (size_t)trow * 1024 + o;
      yp[0]    = acc[mi][ni][0] + ebv;
      yp[1024] = acc[mi][ni][1] + ebv;
      yp[2048] = acc[mi][ni][2] + ebv;
      yp[3072] = acc[mi][ni][3] + ebv;
    }
  }
}

extern "C" void kernel_launch(void* const* d_in, const int* in_sizes, int n_in,
                              void* d_out, int out_size, void* d_ws, size_t ws_size,
                              hipStream_t stream) {
  const float* x      = (const float*)d_in[0];
  const float* w_gate = (const float*)d_in[1];
  const float* weight = (const float*)d_in[2];
  const float* bias   = (const float*)d_in[3];
  const float* res_w  = (const float*)d_in[4];
  const float* res_b  = (const float*)d_in[5];
  const float* c1i    = (const float*)d_in[6];
  const float* c2i    = (const float*)d_in[7];
  const float* c1o    = (const float*)d_in[8];
  const float* c2o    = (const float*)d_in[9];
  const float* c1b    = (const float*)d_in[10];
  const float* c2b    = (const float*)d_in[11];
  float* y = (float*)d_out;

  if (ws_size < WS_NEED) return;

  char* wsb = (char*)d_ws;
  u16*   xbf   = (u16*)(wsb + OFF_XBF);
  u16*   EW    = (u16*)(wsb + OFF_EW);
  u16*   T2t   = (u16*)(wsb + OFF_T2);
  float* pm    = (float*)(wsb + OFF_PM);
  u16*   RWbf  = (u16*)(wsb + OFF_RW);
  float* lgts  = (float*)(wsb + OFF_LG);
  float* g     = (float*)(wsb + OFF_G);
  float* rb    = (float*)(wsb + OFF_RB);

  k_means    <<<dim3(64, 16), 256, 0, stream>>>(x, pm, xbf);
  k_redlogits<<<64, 256, 0, stream>>>(pm, w_gate, lgts);
  k_mergeA   <<<dim3(129, 8), 256, 0, stream>>>(weight, res_w, c1o, c2o, T2t,
                                                bias, res_b, c1b, c2b, rb);
  k_mergeB   <<<dim3(129, 8), 256, 0, stream>>>(T2t, c1i, c2i, res_w, RWbf,
                                                lgts, g, y + 16777216);
  k_combine  <<<512, 256, 0, stream>>>(RWbf, g, EW);
  k_gemm     <<<256, 512, 0, stream>>>(xbf, EW, rb, res_b, g, y);
}